// Round 5
// baseline (274.431 us; speedup 1.0000x reference)
//
#include <hip/hip_runtime.h>
#include <math.h>

// Problem constants (match reference)
constexpr int   B       = 2048;
constexpr int   P       = 4;
constexpr int   D       = 256;       // K of the GEMM
constexpr int   NNEG    = 32768;
constexpr int   NTILES  = NNEG / 64; // per-row exp2-sum partials (64-col patches)
constexpr float TEMP    = 0.05f;
constexpr float ALPHA   = 0.1f;
constexpr float EPS     = 1e-12f;
constexpr float INV_T   = 1.0f / TEMP;
// A-side rows are pre-scaled by (1/T)*log2(e) so the MFMA accumulator is
// directly q = sim/T * log2(e), and exp(sim/T) = exp2(q).  |q| <= ~30 so no
// max-tracking is needed (exp2 stays in fp32 range).
constexpr float SCALE_Q = 28.853900817779268f;

typedef __bf16 bf16x8 __attribute__((ext_vector_type(8)));
typedef float  f32x4  __attribute__((ext_vector_type(4)));

// fp32 -> bf16 (RNE), bit-level
__device__ inline unsigned short f2bf(float f) {
  unsigned int u = __float_as_uint(f);
  u = (u + 0x7fffu + ((u >> 16) & 1u)) >> 16;
  return (unsigned short)u;
}

// ---------------------------------------------------------------------------
// Kernel 1 (fused prep): one wave per work row.
//   rows [0, B)              : normalize anchor, scale by SCALE_Q, cast bf16
//   rows [B, B+NNEG)         : normalize negative, cast bf16
//   rows [B+NNEG, +B*P)      : pos_sim pair dot (exact fp32)
// Thread (0,0) zeroes loss_acc and ticket for kernel 3 (stream-ordered).
// ---------------------------------------------------------------------------
__global__ void prep_kernel(const float* __restrict__ a,
                            const float* __restrict__ pzx,
                            const float* __restrict__ n,
                            unsigned short* __restrict__ a_bf,
                            unsigned short* __restrict__ n_bf,
                            float* __restrict__ pos_sim,
                            float* __restrict__ loss_acc,
                            unsigned int* __restrict__ ticket) {
  if (blockIdx.x == 0 && threadIdx.x == 0) { *loss_acc = 0.0f; *ticket = 0u; }
  int w    = (blockIdx.x * blockDim.x + threadIdx.x) >> 6;
  int lane = threadIdx.x & 63;
  if (w < B + NNEG) {
    const float* src; unsigned short* dst; float post;
    if (w < B) { src = a + (size_t)w * D;       dst = a_bf + (size_t)w * D;       post = SCALE_Q; }
    else       { src = n + (size_t)(w - B) * D; dst = n_bf + (size_t)(w - B) * D; post = 1.0f; }
    float4 v = ((const float4*)src)[lane];
    float ss = v.x * v.x + v.y * v.y + v.z * v.z + v.w * v.w;
#pragma unroll
    for (int off = 32; off > 0; off >>= 1) ss += __shfl_xor(ss, off, 64);
    float inv = post / fmaxf(sqrtf(ss), EPS);
    ushort4 o;
    o.x = f2bf(v.x * inv); o.y = f2bf(v.y * inv);
    o.z = f2bf(v.z * inv); o.w = f2bf(v.w * inv);
    ((ushort4*)dst)[lane] = o;
  } else {
    int pw = w - (B + NNEG);           // 0..B*P-1
    if (pw >= B * P) return;
    int b = pw >> 2;                   // P == 4
    float4 av = ((const float4*)(a + (size_t)b * D))[lane];
    float4 pv = ((const float4*)(pzx + (size_t)pw * D))[lane];
    float d  = av.x * pv.x + av.y * pv.y + av.z * pv.z + av.w * pv.w;
    float sa = av.x * av.x + av.y * av.y + av.z * av.z + av.w * av.w;
    float sp = pv.x * pv.x + pv.y * pv.y + pv.z * pv.z + pv.w * pv.w;
#pragma unroll
    for (int off = 32; off > 0; off >>= 1) {
      d  += __shfl_xor(d, off, 64);
      sa += __shfl_xor(sa, off, 64);
      sp += __shfl_xor(sp, off, 64);
    }
    if (lane == 0) {
      float inva = 1.0f / fmaxf(sqrtf(sa), EPS);
      float invp = 1.0f / fmaxf(sqrtf(sp), EPS);
      pos_sim[pw] = d * inva * invp * INV_T;
    }
  }
}

// ---------------------------------------------------------------------------
// Kernel 2: bf16 MFMA GEMM fused with exp2-sum partials.
// 128x128 tile, 4 waves (2x2), each wave 64x64 = 4x4 mfma_f32_16x16x32_bf16.
// BK=64, K=256 -> 4 iterations.
//
// REGISTER-STAGED pipeline, SINGLE 32 KB LDS buffer (keeps 5 blocks/CU; the
// round-4 64 KB double-buffer cut occupancy 26->20% and REGRESSED 56->68 us):
//   load_regs(0)
//   iter: [barrier] -> ds_write(regs) -> barrier -> load_regs(next) -> MFMA
// The global loads for iter i+1 are issued after the LAST barrier of iter i,
// so the compiler's mandatory vmcnt(0)-before-s_barrier drains loads that
// have had the whole compute phase (~400+ cyc) in flight.
//
// XCD swizzle: flat 4096-block grid; block id -> xcd = id&7 handles n-tiles
// [xcd*32, xcd*32+32) = 2 MB of N, fitting the 4 MB per-XCD L2, so the 16
// m-passes over each n-tile hit L2 after the first.
//
// LDS bank-conflict-free XOR swizzle via SOURCE permutation (round 3,
// measured 1.26e7 -> 0): lane (lrow=l>>3, cs=l&7) fetches global 16B-chunk
// (cs ^ lrow) of row lrow; chunk c of row r sits at LDS position c ^ (r&7);
// fragment reads use p = chunk ^ (lane&7) (row&7 == lane&7 for all reads).
//
// Epilogue: acc holds q = sim/T*log2e; per row, sum exp2(q) over the wave's
// 64 cols via 16-lane shuffle reduce -> part_s (no max tracking needed).
// ---------------------------------------------------------------------------
constexpr int BM = 128, BN = 128, BK = 64;

__global__ __launch_bounds__(256) void negsim_mfma_kernel(
    const unsigned short* __restrict__ Abf,  // [B][D] normalized*SCALE_Q bf16
    const unsigned short* __restrict__ Nbf,  // [NNEG][D] normalized bf16
    float* __restrict__ part_s) {            // [B][NTILES]
  __shared__ unsigned short As[BM * BK];  // 16 KB
  __shared__ unsigned short Bs[BN * BK];  // 16 KB

  const int tid  = threadIdx.x;
  const int wave = tid >> 6;
  const int lane = tid & 63;
  const int wx   = wave & 1;   // N direction
  const int wy   = wave >> 1;  // M direction

  // XCD-aware decode of flat block id
  const int id   = blockIdx.x;
  const int xcd  = id & 7;
  const int j    = id >> 3;            // 0..511
  const int nblk = xcd * 32 + (j & 31);  // 0..255
  const int mblk = j >> 5;             // 0..15
  const int m0   = mblk * BM;
  const int n0   = nblk * BN;

  const int lrow = lane >> 3;                    // 0..7
  const int scol = ((lane & 7) ^ lrow) * 8;      // swizzled source k-chunk

  f32x4 acc[4][4] = {};
  uint4 ar[4], br[4];

  auto load_regs = [&](int k0) {
#pragma unroll
    for (int i = 0; i < 4; i++) {
      const int r0 = (wave * 4 + i) * 8;
      ar[i] = *(const uint4*)(Abf + (size_t)(m0 + r0 + lrow) * D + k0 + scol);
      br[i] = *(const uint4*)(Nbf + (size_t)(n0 + r0 + lrow) * D + k0 + scol);
    }
  };
  auto write_lds = [&]() {
#pragma unroll
    for (int i = 0; i < 4; i++) {
      const int r0 = (wave * 4 + i) * 8;
      *(uint4*)(As + r0 * BK + lane * 8) = ar[i];  // lane-linear: conflict-free
      *(uint4*)(Bs + r0 * BK + lane * 8) = br[i];
    }
  };

  load_regs(0);

#pragma unroll
  for (int it = 0; it < D / BK; it++) {
    if (it) __syncthreads();       // prior-iter readers done
    write_lds();                   // waits vmcnt on the prefetched regs
    __syncthreads();               // writes visible to all waves
    if (it + 1 < D / BK) load_regs((it + 1) * BK);  // in flight during MFMA
#pragma unroll
    for (int kk = 0; kk < BK; kk += 32) {
      const int p = (((kk >> 3) + (lane >> 4)) ^ (lane & 7)) * 8;
      bf16x8 af[4], bfr[4];
#pragma unroll
      for (int mi = 0; mi < 4; mi++)
        af[mi] = *(const bf16x8*)&As[(wy * 64 + mi * 16 + (lane & 15)) * BK + p];
#pragma unroll
      for (int ni = 0; ni < 4; ni++)
        bfr[ni] = *(const bf16x8*)&Bs[(wx * 64 + ni * 16 + (lane & 15)) * BK + p];
#pragma unroll
      for (int mi = 0; mi < 4; mi++)
#pragma unroll
        for (int ni = 0; ni < 4; ni++)
          acc[mi][ni] = __builtin_amdgcn_mfma_f32_16x16x32_bf16(
              af[mi], bfr[ni], acc[mi][ni], 0, 0, 0);
    }
  }

  // Epilogue: C/D layout row = mi*16 + (lane>>4)*4 + r, col = ni*16+(lane&15).
#pragma unroll
  for (int mi = 0; mi < 4; mi++) {
#pragma unroll
    for (int r = 0; r < 4; r++) {
      float s = __builtin_amdgcn_exp2f(acc[mi][0][r]) +
                __builtin_amdgcn_exp2f(acc[mi][1][r]) +
                __builtin_amdgcn_exp2f(acc[mi][2][r]) +
                __builtin_amdgcn_exp2f(acc[mi][3][r]);
#pragma unroll
      for (int off = 1; off < 16; off <<= 1) s += __shfl_xor(s, off, 64);
      if ((lane & 15) == 0) {
        int row = m0 + wy * 64 + mi * 16 + (lane >> 4) * 4 + r;
        part_s[(size_t)row * NTILES + (nblk * 2 + wx)] = s;
      }
    }
  }
}

// ---------------------------------------------------------------------------
// Kernel 3: per-anchor loss + final reduce.  32 blocks x 256 threads; each
// QUAD of threads handles one anchor (4-way split of the 512-partial sum).
// One atomicAdd per block (32 total, ~1 us serialized worst case) + ticket;
// last block writes out[0].
// ---------------------------------------------------------------------------
__global__ void loss_kernel(const float* __restrict__ part_s,
                            const float* __restrict__ pos_sim,
                            const int* __restrict__ counts,
                            float* __restrict__ loss_acc,
                            unsigned int* __restrict__ ticket,
                            float* __restrict__ out) {
  const int tid = threadIdx.x;
  const int b   = blockIdx.x * 64 + (tid >> 2);
  const int sub = tid & 3;
  const float* ps = part_s + (size_t)b * NTILES;
  float s = 0.0f;
#pragma unroll
  for (int i = 0; i < NTILES / 4; i++) s += ps[sub + i * 4];
  s += __shfl_xor(s, 1, 64);
  s += __shfl_xor(s, 2, 64);   // quad now holds full S in every sub-lane

  float acc = 0.0f;
  if (sub == 0) {
    float L = logf(s);  // neg_lse in natural-log units
    float p0 = pos_sim[b * P + 0], p1 = pos_sim[b * P + 1];
    float p2 = pos_sim[b * P + 2], p3 = pos_sim[b * P + 3];
    int cnt = counts[b];
    float pj[P] = {p0, p1, p2, p3};
#pragma unroll
    for (int jj = 0; jj < P; jj++) {
      if (jj < cnt) {
        float hi = fmaxf(pj[jj], L), lo = fminf(pj[jj], L);
        acc += hi + log1pf(__expf(lo - hi)) - pj[jj];
      }
    }
    float mp = fmaxf(fmaxf(p0, p1), fmaxf(p2, p3));
    float e0 = __expf(p0 - mp), e1 = __expf(p1 - mp);
    float e2 = __expf(p2 - mp), e3 = __expf(p3 - mp);
    float se = e0 + e1 + e2 + e3;
    float wps = (e0 * p0 + e1 * p1 + e2 * p2 + e3 * p3) / se;
    if (cnt > 1) {
      float hi = fmaxf(wps, L), lo = fminf(wps, L);
      acc += ALPHA * (hi + log1pf(__expf(lo - hi)) - wps);
    }
  }
  // block reduce (only sub==0 lanes carry nonzero)
#pragma unroll
  for (int off = 32; off > 0; off >>= 1) acc += __shfl_xor(acc, off, 64);
  __shared__ float sa[4];
  int wid = tid >> 6, lane = tid & 63;
  if (lane == 0) sa[wid] = acc;
  __syncthreads();
  if (tid == 0) {
    atomicAdd(loss_acc, sa[0] + sa[1] + sa[2] + sa[3]);
    __threadfence();
    unsigned int t = atomicAdd(ticket, 1u);
    if (t == (unsigned int)gridDim.x - 1u) {
      float total = atomicAdd(loss_acc, 0.0f);  // atomic read-back
      out[0] = total / (float)B;
    }
  }
}

// ---------------------------------------------------------------------------
extern "C" void kernel_launch(void* const* d_in, const int* in_sizes, int n_in,
                              void* d_out, int out_size, void* d_ws,
                              size_t ws_size, hipStream_t stream) {
  const float* anc    = (const float*)d_in[0];
  const float* pos    = (const float*)d_in[1];
  const float* neg    = (const float*)d_in[2];
  const int*   counts = (const int*)d_in[3];
  float* out = (float*)d_out;

  // Workspace layout: ~21.1 MB
  unsigned short* a_bf = (unsigned short*)d_ws;          // B*D      (1 MB)
  unsigned short* n_bf = a_bf + (size_t)B * D;           // NNEG*D   (16 MB)
  float* part_s  = (float*)(n_bf + (size_t)NNEG * D);    // B*NTILES (4 MB)
  float* pos_sim = part_s + (size_t)B * NTILES;          // B*P
  float* loss_acc = pos_sim + B * P;                     // 1
  unsigned int* ticket = (unsigned int*)(loss_acc + 1);  // 1

  // 43008 work-rows (norm-cast B+NNEG, possim B*P), 4 waves/block
  prep_kernel<<<(B + NNEG + B * P) / 4, 256, 0, stream>>>(
      anc, pos, neg, a_bf, n_bf, pos_sim, loss_acc, ticket);

  negsim_mfma_kernel<<<4096, 256, 0, stream>>>(a_bf, n_bf, part_s);

  loss_kernel<<<B / 64, 256, 0, stream>>>(part_s, pos_sim, counts,
                                          loss_acc, ticket, out);
}

// Round 6
// 221.627 us; speedup vs baseline: 1.2383x; 1.2383x over previous
//
#include <hip/hip_runtime.h>
#include <math.h>

// Problem constants (match reference)
constexpr int   B       = 2048;
constexpr int   P       = 4;
constexpr int   D       = 256;       // K of the GEMM
constexpr int   NNEG    = 32768;
constexpr int   NTILES  = NNEG / 64; // per-row exp2-sum partials (64-col patches)
constexpr float TEMP    = 0.05f;
constexpr float ALPHA   = 0.1f;
constexpr float EPS     = 1e-12f;
constexpr float INV_T   = 1.0f / TEMP;
// A-side rows are pre-scaled by (1/T)*log2(e) so the MFMA accumulator is
// directly q = sim/T * log2(e), and exp(sim/T) = exp2(q).  |q| <= ~30 so no
// max-tracking is needed (exp2 stays in fp32 range).
constexpr float SCALE_Q = 28.853900817779268f;

typedef __bf16 bf16x8 __attribute__((ext_vector_type(8)));
typedef float  f32x4  __attribute__((ext_vector_type(4)));

// fp32 -> bf16 (RNE), bit-level
__device__ inline unsigned short f2bf(float f) {
  unsigned int u = __float_as_uint(f);
  u = (u + 0x7fffu + ((u >> 16) & 1u)) >> 16;
  return (unsigned short)u;
}

// ---------------------------------------------------------------------------
// Kernel 1 (fused prep): one wave per work row.
//   rows [0, B)              : normalize anchor, scale by SCALE_Q, cast bf16
//   rows [B, B+NNEG)         : normalize negative, cast bf16
//   rows [B+NNEG, +B*P)      : pos_sim pair dot (exact fp32)
// Thread (0,0) zeroes loss_acc and ticket for kernel 3 (stream-ordered).
// ---------------------------------------------------------------------------
__global__ void prep_kernel(const float* __restrict__ a,
                            const float* __restrict__ pzx,
                            const float* __restrict__ n,
                            unsigned short* __restrict__ a_bf,
                            unsigned short* __restrict__ n_bf,
                            float* __restrict__ pos_sim,
                            float* __restrict__ loss_acc,
                            unsigned int* __restrict__ ticket) {
  if (blockIdx.x == 0 && threadIdx.x == 0) { *loss_acc = 0.0f; *ticket = 0u; }
  int w    = (blockIdx.x * blockDim.x + threadIdx.x) >> 6;
  int lane = threadIdx.x & 63;
  if (w < B + NNEG) {
    const float* src; unsigned short* dst; float post;
    if (w < B) { src = a + (size_t)w * D;       dst = a_bf + (size_t)w * D;       post = SCALE_Q; }
    else       { src = n + (size_t)(w - B) * D; dst = n_bf + (size_t)(w - B) * D; post = 1.0f; }
    float4 v = ((const float4*)src)[lane];
    float ss = v.x * v.x + v.y * v.y + v.z * v.z + v.w * v.w;
#pragma unroll
    for (int off = 32; off > 0; off >>= 1) ss += __shfl_xor(ss, off, 64);
    float inv = post / fmaxf(sqrtf(ss), EPS);
    ushort4 o;
    o.x = f2bf(v.x * inv); o.y = f2bf(v.y * inv);
    o.z = f2bf(v.z * inv); o.w = f2bf(v.w * inv);
    ((ushort4*)dst)[lane] = o;
  } else {
    int pw = w - (B + NNEG);           // 0..B*P-1
    if (pw >= B * P) return;
    int b = pw >> 2;                   // P == 4
    float4 av = ((const float4*)(a + (size_t)b * D))[lane];
    float4 pv = ((const float4*)(pzx + (size_t)pw * D))[lane];
    float d  = av.x * pv.x + av.y * pv.y + av.z * pv.z + av.w * pv.w;
    float sa = av.x * av.x + av.y * av.y + av.z * av.z + av.w * av.w;
    float sp = pv.x * pv.x + pv.y * pv.y + pv.z * pv.z + pv.w * pv.w;
#pragma unroll
    for (int off = 32; off > 0; off >>= 1) {
      d  += __shfl_xor(d, off, 64);
      sa += __shfl_xor(sa, off, 64);
      sp += __shfl_xor(sp, off, 64);
    }
    if (lane == 0) {
      float inva = 1.0f / fmaxf(sqrtf(sa), EPS);
      float invp = 1.0f / fmaxf(sqrtf(sp), EPS);
      pos_sim[pw] = d * inva * invp * INV_T;
    }
  }
}

// ---------------------------------------------------------------------------
// Kernel 2: bf16 MFMA GEMM fused with exp2-sum partials.  NO LDS.
//
// K=256 is tiny, so skip shared-memory staging entirely: the 16x16x32 MFMA
// A-operand layout (A[m=lane&15][k=(lane>>4)*8+j], j=0..7) is one 16 B
// global_load_dwordx4 per fragment, loaded STRAIGHT from the row-major bf16
// matrices.  A wave's fragment load = 16 rows x 64 B = 16 fully-consumed
// cache lines.  No barriers, no vmcnt(0) drains, no bank conflicts, no
// cross-phase register liveness (round-5's lambda-captured prefetch arrays
// were demoted to scratch: WRITE_SIZE 16->504 MB.  Fragments here are
// loop-local per unrolled iteration).
//
// Traffic: per 128x128 block, 64 KB (A) + 64 KB (B) fragment reads, grid
// total 512 MB served from per-XCD L2 (XCD swizzle: block id&7 -> xcd owns
// n-strip of 32 tiles = 2 MB of N + all of A (1 MB) < 4 MB L2).  At 34.5
// TB/s that's ~15 us, balanced against the 13.8 us MFMA floor.
//
// 128x128 tile, 4 waves (2x2), each wave 64x64 = 4x4 mfma_f32_16x16x32_bf16.
// Epilogue: acc holds q = sim/T*log2e (A pre-scaled); per row, sum exp2(q)
// over the wave's 64 cols via 16-lane shuffle reduce -> part_s.
// ---------------------------------------------------------------------------
constexpr int BM = 128, BN = 128;

__global__ __launch_bounds__(256, 3) void negsim_mfma_kernel(
    const unsigned short* __restrict__ Abf,  // [B][D] normalized*SCALE_Q bf16
    const unsigned short* __restrict__ Nbf,  // [NNEG][D] normalized bf16
    float* __restrict__ part_s) {            // [B][NTILES]
  const int tid  = threadIdx.x;
  const int wave = tid >> 6;
  const int lane = tid & 63;
  const int wx   = wave & 1;   // N direction
  const int wy   = wave >> 1;  // M direction

  // XCD-aware decode of flat block id
  const int id   = blockIdx.x;
  const int xcd  = id & 7;
  const int j    = id >> 3;              // 0..511
  const int nblk = xcd * 32 + (j & 31);  // 0..255
  const int mblk = j >> 5;               // 0..15
  const int m0   = mblk * BM;
  const int n0   = nblk * BN;

  const int r = lane & 15;   // row within 16-row fragment
  const int q = lane >> 4;   // k-quad: this lane's 8-elem (16 B) k-chunk

  const unsigned short* Ap = Abf + (size_t)(m0 + wy * 64 + r) * D + q * 8;
  const unsigned short* Bp = Nbf + (size_t)(n0 + wx * 64 + r) * D + q * 8;

  f32x4 acc[4][4] = {};

#pragma unroll
  for (int kk = 0; kk < D; kk += 32) {
    bf16x8 af[4], bfr[4];
#pragma unroll
    for (int mi = 0; mi < 4; mi++)
      af[mi] = *(const bf16x8*)(Ap + (size_t)mi * 16 * D + kk);
#pragma unroll
    for (int ni = 0; ni < 4; ni++)
      bfr[ni] = *(const bf16x8*)(Bp + (size_t)ni * 16 * D + kk);
#pragma unroll
    for (int mi = 0; mi < 4; mi++)
#pragma unroll
      for (int ni = 0; ni < 4; ni++)
        acc[mi][ni] = __builtin_amdgcn_mfma_f32_16x16x32_bf16(
            af[mi], bfr[ni], acc[mi][ni], 0, 0, 0);
  }

  // Epilogue: C/D layout row = mi*16 + (lane>>4)*4 + r, col = ni*16+(lane&15).
#pragma unroll
  for (int mi = 0; mi < 4; mi++) {
#pragma unroll
    for (int rr = 0; rr < 4; rr++) {
      float s = __builtin_amdgcn_exp2f(acc[mi][0][rr]) +
                __builtin_amdgcn_exp2f(acc[mi][1][rr]) +
                __builtin_amdgcn_exp2f(acc[mi][2][rr]) +
                __builtin_amdgcn_exp2f(acc[mi][3][rr]);
#pragma unroll
      for (int off = 1; off < 16; off <<= 1) s += __shfl_xor(s, off, 64);
      if ((lane & 15) == 0) {
        int row = m0 + wy * 64 + mi * 16 + (lane >> 4) * 4 + rr;
        part_s[(size_t)row * NTILES + (nblk * 2 + wx)] = s;
      }
    }
  }
}

// ---------------------------------------------------------------------------
// Kernel 3: per-anchor loss + final reduce.  32 blocks x 256 threads; each
// QUAD of threads handles one anchor (4-way split of the 512-partial sum).
// One atomicAdd per block (32 total) + ticket; last block writes out[0].
// ---------------------------------------------------------------------------
__global__ void loss_kernel(const float* __restrict__ part_s,
                            const float* __restrict__ pos_sim,
                            const int* __restrict__ counts,
                            float* __restrict__ loss_acc,
                            unsigned int* __restrict__ ticket,
                            float* __restrict__ out) {
  const int tid = threadIdx.x;
  const int b   = blockIdx.x * 64 + (tid >> 2);
  const int sub = tid & 3;
  const float* ps = part_s + (size_t)b * NTILES;
  float s = 0.0f;
#pragma unroll
  for (int i = 0; i < NTILES / 4; i++) s += ps[sub + i * 4];
  s += __shfl_xor(s, 1, 64);
  s += __shfl_xor(s, 2, 64);   // quad now holds full S in every sub-lane

  float acc = 0.0f;
  if (sub == 0) {
    float L = logf(s);  // neg_lse in natural-log units
    float p0 = pos_sim[b * P + 0], p1 = pos_sim[b * P + 1];
    float p2 = pos_sim[b * P + 2], p3 = pos_sim[b * P + 3];
    int cnt = counts[b];
    float pj[P] = {p0, p1, p2, p3};
#pragma unroll
    for (int jj = 0; jj < P; jj++) {
      if (jj < cnt) {
        float hi = fmaxf(pj[jj], L), lo = fminf(pj[jj], L);
        acc += hi + log1pf(__expf(lo - hi)) - pj[jj];
      }
    }
    float mp = fmaxf(fmaxf(p0, p1), fmaxf(p2, p3));
    float e0 = __expf(p0 - mp), e1 = __expf(p1 - mp);
    float e2 = __expf(p2 - mp), e3 = __expf(p3 - mp);
    float se = e0 + e1 + e2 + e3;
    float wps = (e0 * p0 + e1 * p1 + e2 * p2 + e3 * p3) / se;
    if (cnt > 1) {
      float hi = fmaxf(wps, L), lo = fminf(wps, L);
      acc += ALPHA * (hi + log1pf(__expf(lo - hi)) - wps);
    }
  }
  // block reduce (only sub==0 lanes carry nonzero)
#pragma unroll
  for (int off = 32; off > 0; off >>= 1) acc += __shfl_xor(acc, off, 64);
  __shared__ float sa[4];
  int wid = tid >> 6, lane = tid & 63;
  if (lane == 0) sa[wid] = acc;
  __syncthreads();
  if (tid == 0) {
    atomicAdd(loss_acc, sa[0] + sa[1] + sa[2] + sa[3]);
    __threadfence();
    unsigned int t = atomicAdd(ticket, 1u);
    if (t == (unsigned int)gridDim.x - 1u) {
      float total = atomicAdd(loss_acc, 0.0f);  // atomic read-back
      out[0] = total / (float)B;
    }
  }
}

// ---------------------------------------------------------------------------
extern "C" void kernel_launch(void* const* d_in, const int* in_sizes, int n_in,
                              void* d_out, int out_size, void* d_ws,
                              size_t ws_size, hipStream_t stream) {
  const float* anc    = (const float*)d_in[0];
  const float* pos    = (const float*)d_in[1];
  const float* neg    = (const float*)d_in[2];
  const int*   counts = (const int*)d_in[3];
  float* out = (float*)d_out;

  // Workspace layout: ~21.1 MB
  unsigned short* a_bf = (unsigned short*)d_ws;          // B*D      (1 MB)
  unsigned short* n_bf = a_bf + (size_t)B * D;           // NNEG*D   (16 MB)
  float* part_s  = (float*)(n_bf + (size_t)NNEG * D);    // B*NTILES (4 MB)
  float* pos_sim = part_s + (size_t)B * NTILES;          // B*P
  float* loss_acc = pos_sim + B * P;                     // 1
  unsigned int* ticket = (unsigned int*)(loss_acc + 1);  // 1

  // 43008 work-rows (norm-cast B+NNEG, possim B*P), 4 waves/block
  prep_kernel<<<(B + NNEG + B * P) / 4, 256, 0, stream>>>(
      anc, pos, neg, a_bf, n_bf, pos_sim, loss_acc, ticket);

  negsim_mfma_kernel<<<4096, 256, 0, stream>>>(a_bf, n_bf, part_s);

  loss_kernel<<<B / 64, 256, 0, stream>>>(part_s, pos_sim, counts,
                                          loss_acc, ticket, out);
}

// Round 7
// 148.388 us; speedup vs baseline: 1.8494x; 1.4936x over previous
//
#include <hip/hip_runtime.h>
#include <math.h>

// Problem constants (match reference)
constexpr int   B       = 2048;
constexpr int   P       = 4;
constexpr int   D       = 256;       // K of the GEMM
constexpr int   NNEG    = 32768;
constexpr int   NTILES  = NNEG / 64; // per-row exp2-sum partials (64-col patches)
constexpr float TEMP    = 0.05f;
constexpr float ALPHA   = 0.1f;
constexpr float EPS     = 1e-12f;
constexpr float INV_T   = 1.0f / TEMP;
// A-side rows are pre-scaled by (1/T)*log2(e) so the MFMA accumulator is
// directly q = sim/T * log2(e), and exp(sim/T) = exp2(q).  |q| <= ~30 so no
// max-tracking is needed (exp2 stays in fp32 range).
constexpr float SCALE_Q = 28.853900817779268f;

typedef __bf16 bf16x8 __attribute__((ext_vector_type(8)));
typedef float  f32x4  __attribute__((ext_vector_type(4)));

// fp32 -> bf16 (RNE), bit-level
__device__ inline unsigned short f2bf(float f) {
  unsigned int u = __float_as_uint(f);
  u = (u + 0x7fffu + ((u >> 16) & 1u)) >> 16;
  return (unsigned short)u;
}

// ---------------------------------------------------------------------------
// FRAGMENT-MAJOR layout: element (row, k) of a [R x 256] bf16 matrix lives at
//   p*4096 + c*512 + q*128 + r*8 + j
// where p=row>>4, r=row&15, c=k>>5, q=(k>>3)&3, j=k&7.
// A (panel p, chunk c) fragment is 1024 contiguous bytes; MFMA lane l=r+16q
// reads its 16 B at byte offset l*16 -> one perfectly-coalesced
// global_load_dwordx4 per fragment.  (Round 6's row-major direct loads hit 16
// scattered cache lines per instruction -> issue-bound, MfmaUtil 10%.)
// k is identically permuted for A and B, so the dot product is unchanged.
// ---------------------------------------------------------------------------

// ---------------------------------------------------------------------------
// Kernel 1 (fused prep): one wave per work row.
//   rows [0, B)         : normalize anchor, scale SCALE_Q, cast bf16 -> frag-major
//   rows [B, B+NNEG)    : normalize negative, cast bf16 -> frag-major
//   rows [B+NNEG,+B*P)  : pos_sim pair dot (exact fp32)
// Lane holds k=4*lane..4*lane+3 -> frag-major dst offset (ushort4, 8 B):
//   c=lane>>3, q=(lane>>1)&3, j0=(lane&1)*4.
// Thread (0,0) zeroes loss_acc and ticket for kernel 3 (stream-ordered).
// ---------------------------------------------------------------------------
__global__ void prep_kernel(const float* __restrict__ a,
                            const float* __restrict__ pzx,
                            const float* __restrict__ n,
                            unsigned short* __restrict__ a_bf,
                            unsigned short* __restrict__ n_bf,
                            float* __restrict__ pos_sim,
                            float* __restrict__ loss_acc,
                            unsigned int* __restrict__ ticket) {
  if (blockIdx.x == 0 && threadIdx.x == 0) { *loss_acc = 0.0f; *ticket = 0u; }
  int w    = (blockIdx.x * blockDim.x + threadIdx.x) >> 6;
  int lane = threadIdx.x & 63;
  if (w < B + NNEG) {
    const float* src; unsigned short* dstm; int row; float post;
    if (w < B) { src = a + (size_t)w * D;       dstm = a_bf; row = w;     post = SCALE_Q; }
    else       { src = n + (size_t)(w - B) * D; dstm = n_bf; row = w - B; post = 1.0f; }
    float4 v = ((const float4*)src)[lane];
    float ss = v.x * v.x + v.y * v.y + v.z * v.z + v.w * v.w;
#pragma unroll
    for (int off = 32; off > 0; off >>= 1) ss += __shfl_xor(ss, off, 64);
    float inv = post / fmaxf(sqrtf(ss), EPS);
    ushort4 o;
    o.x = f2bf(v.x * inv); o.y = f2bf(v.y * inv);
    o.z = f2bf(v.z * inv); o.w = f2bf(v.w * inv);
    const int p = row >> 4, r = row & 15;
    const int c = lane >> 3, q = (lane >> 1) & 3, j0 = (lane & 1) * 4;
    *(ushort4*)(dstm + (size_t)p * 4096 + c * 512 + q * 128 + r * 8 + j0) = o;
  } else {
    int pw = w - (B + NNEG);           // 0..B*P-1
    if (pw >= B * P) return;
    int b = pw >> 2;                   // P == 4
    float4 av = ((const float4*)(a + (size_t)b * D))[lane];
    float4 pv = ((const float4*)(pzx + (size_t)pw * D))[lane];
    float d  = av.x * pv.x + av.y * pv.y + av.z * pv.z + av.w * pv.w;
    float sa = av.x * av.x + av.y * av.y + av.z * av.z + av.w * av.w;
    float sp = pv.x * pv.x + pv.y * pv.y + pv.z * pv.z + pv.w * pv.w;
#pragma unroll
    for (int off = 32; off > 0; off >>= 1) {
      d  += __shfl_xor(d, off, 64);
      sa += __shfl_xor(sa, off, 64);
      sp += __shfl_xor(sp, off, 64);
    }
    if (lane == 0) {
      float inva = 1.0f / fmaxf(sqrtf(sa), EPS);
      float invp = 1.0f / fmaxf(sqrtf(sp), EPS);
      pos_sim[pw] = d * inva * invp * INV_T;
    }
  }
}

// ---------------------------------------------------------------------------
// Kernel 2: bf16 MFMA GEMM fused with exp2-sum partials.  NO LDS, no
// barriers; fragments loaded straight from fragment-major global (coalesced
// 1 KB per instruction), depth-1 ping-pong prefetch (named arrays under full
// unroll -> SSA; NO lambda-captured state, which round 5 proved spills).
//
// 128x128 tile, 4 waves (2x2), each wave 64x64 = 4x4 mfma_f32_16x16x32_bf16.
// 8 k-chunks of 32.  XCD swizzle: block id&7 -> xcd owns a 32-ntile strip
// (2 MB of N) + all of A (1 MB) < 4 MB per-XCD L2.
//
// Epilogue: acc holds q = sim/T*log2e (A pre-scaled); per row, sum exp2(q)
// over the wave's 64 cols via 16-lane shuffle reduce -> part_s.
// ---------------------------------------------------------------------------
constexpr int BM = 128, BN = 128;

__global__ __launch_bounds__(256, 4) void negsim_mfma_kernel(
    const unsigned short* __restrict__ Af,   // frag-major [B][256]
    const unsigned short* __restrict__ Nf,   // frag-major [NNEG][256]
    float* __restrict__ part_s) {            // [B][NTILES]
  const int tid  = threadIdx.x;
  const int wave = tid >> 6;
  const int lane = tid & 63;
  const int wx   = wave & 1;   // N direction
  const int wy   = wave >> 1;  // M direction

  // XCD-aware decode of flat block id
  const int id   = blockIdx.x;
  const int xcd  = id & 7;
  const int j    = id >> 3;              // 0..511
  const int nblk = xcd * 32 + (j & 31);  // 0..255
  const int mblk = j >> 5;               // 0..15
  const int m0   = mblk * BM;
  const int n0   = nblk * BN;

  // Wave's A/B fragment base: panel (m0>>4 + wy*4 + mi), chunk c.
  const unsigned short* Ap = Af + (size_t)((m0 >> 4) + wy * 4) * 4096 + lane * 8;
  const unsigned short* Bp = Nf + (size_t)((n0 >> 4) + wx * 4) * 4096 + lane * 8;

  f32x4 acc[4][4] = {};
  bf16x8 a0[4], b0[4], a1[4], b1[4];

#pragma unroll
  for (int mi = 0; mi < 4; mi++) {
    a0[mi] = *(const bf16x8*)(Ap + (size_t)mi * 4096);
    b0[mi] = *(const bf16x8*)(Bp + (size_t)mi * 4096);
  }

#pragma unroll
  for (int c = 0; c < 8; c += 2) {
    if (c + 1 < 8) {
#pragma unroll
      for (int mi = 0; mi < 4; mi++) {
        a1[mi] = *(const bf16x8*)(Ap + (size_t)mi * 4096 + (c + 1) * 512);
        b1[mi] = *(const bf16x8*)(Bp + (size_t)mi * 4096 + (c + 1) * 512);
      }
    }
#pragma unroll
    for (int mi = 0; mi < 4; mi++)
#pragma unroll
      for (int ni = 0; ni < 4; ni++)
        acc[mi][ni] = __builtin_amdgcn_mfma_f32_16x16x32_bf16(
            a0[mi], b0[ni], acc[mi][ni], 0, 0, 0);
    if (c + 2 < 8) {
#pragma unroll
      for (int mi = 0; mi < 4; mi++) {
        a0[mi] = *(const bf16x8*)(Ap + (size_t)mi * 4096 + (c + 2) * 512);
        b0[mi] = *(const bf16x8*)(Bp + (size_t)mi * 4096 + (c + 2) * 512);
      }
    }
#pragma unroll
    for (int mi = 0; mi < 4; mi++)
#pragma unroll
      for (int ni = 0; ni < 4; ni++)
        acc[mi][ni] = __builtin_amdgcn_mfma_f32_16x16x32_bf16(
            a1[mi], b1[ni], acc[mi][ni], 0, 0, 0);
  }

  // Epilogue: C/D layout row = mi*16 + (lane>>4)*4 + rr, col = ni*16+(lane&15).
#pragma unroll
  for (int mi = 0; mi < 4; mi++) {
#pragma unroll
    for (int rr = 0; rr < 4; rr++) {
      float s = __builtin_amdgcn_exp2f(acc[mi][0][rr]) +
                __builtin_amdgcn_exp2f(acc[mi][1][rr]) +
                __builtin_amdgcn_exp2f(acc[mi][2][rr]) +
                __builtin_amdgcn_exp2f(acc[mi][3][rr]);
#pragma unroll
      for (int off = 1; off < 16; off <<= 1) s += __shfl_xor(s, off, 64);
      if ((lane & 15) == 0) {
        int row = m0 + wy * 64 + mi * 16 + (lane >> 4) * 4 + rr;
        part_s[(size_t)row * NTILES + (nblk * 2 + wx)] = s;
      }
    }
  }
}

// ---------------------------------------------------------------------------
// Kernel 3: per-anchor loss + final reduce.  128 blocks x 256 threads; each
// 16-lane group handles one anchor (16-way split of the 512-partial sum).
// One atomicAdd per block (128 total) + ticket; last block writes out[0].
// ---------------------------------------------------------------------------
__global__ void loss_kernel(const float* __restrict__ part_s,
                            const float* __restrict__ pos_sim,
                            const int* __restrict__ counts,
                            float* __restrict__ loss_acc,
                            unsigned int* __restrict__ ticket,
                            float* __restrict__ out) {
  const int tid = threadIdx.x;
  const int b   = blockIdx.x * 16 + (tid >> 4);
  const int sub = tid & 15;
  const float* ps = part_s + (size_t)b * NTILES;
  float s = 0.0f;
#pragma unroll
  for (int i = 0; i < NTILES / 16; i++) s += ps[sub + i * 16];
  s += __shfl_xor(s, 1, 64);
  s += __shfl_xor(s, 2, 64);
  s += __shfl_xor(s, 4, 64);
  s += __shfl_xor(s, 8, 64);   // 16-lane group now holds full S

  float acc = 0.0f;
  if (sub == 0) {
    float L = logf(s);  // neg_lse in natural-log units
    float p0 = pos_sim[b * P + 0], p1 = pos_sim[b * P + 1];
    float p2 = pos_sim[b * P + 2], p3 = pos_sim[b * P + 3];
    int cnt = counts[b];
    float pj[P] = {p0, p1, p2, p3};
#pragma unroll
    for (int jj = 0; jj < P; jj++) {
      if (jj < cnt) {
        float hi = fmaxf(pj[jj], L), lo = fminf(pj[jj], L);
        acc += hi + log1pf(__expf(lo - hi)) - pj[jj];
      }
    }
    float mp = fmaxf(fmaxf(p0, p1), fmaxf(p2, p3));
    float e0 = __expf(p0 - mp), e1 = __expf(p1 - mp);
    float e2 = __expf(p2 - mp), e3 = __expf(p3 - mp);
    float se = e0 + e1 + e2 + e3;
    float wps = (e0 * p0 + e1 * p1 + e2 * p2 + e3 * p3) / se;
    if (cnt > 1) {
      float hi = fmaxf(wps, L), lo = fminf(wps, L);
      acc += ALPHA * (hi + log1pf(__expf(lo - hi)) - wps);
    }
  }
  // block reduce (only sub==0 lanes carry nonzero)
#pragma unroll
  for (int off = 32; off > 0; off >>= 1) acc += __shfl_xor(acc, off, 64);
  __shared__ float sa[4];
  int wid = tid >> 6, lane = tid & 63;
  if (lane == 0) sa[wid] = acc;
  __syncthreads();
  if (tid == 0) {
    atomicAdd(loss_acc, sa[0] + sa[1] + sa[2] + sa[3]);
    __threadfence();
    unsigned int t = atomicAdd(ticket, 1u);
    if (t == (unsigned int)gridDim.x - 1u) {
      float total = atomicAdd(loss_acc, 0.0f);  // atomic read-back
      out[0] = total / (float)B;
    }
  }
}

// ---------------------------------------------------------------------------
extern "C" void kernel_launch(void* const* d_in, const int* in_sizes, int n_in,
                              void* d_out, int out_size, void* d_ws,
                              size_t ws_size, hipStream_t stream) {
  const float* anc    = (const float*)d_in[0];
  const float* pos    = (const float*)d_in[1];
  const float* neg    = (const float*)d_in[2];
  const int*   counts = (const int*)d_in[3];
  float* out = (float*)d_out;

  // Workspace layout: ~21.1 MB
  unsigned short* a_bf = (unsigned short*)d_ws;          // B*D      (1 MB)
  unsigned short* n_bf = a_bf + (size_t)B * D;           // NNEG*D   (16 MB)
  float* part_s  = (float*)(n_bf + (size_t)NNEG * D);    // B*NTILES (4 MB)
  float* pos_sim = part_s + (size_t)B * NTILES;          // B*P
  float* loss_acc = pos_sim + B * P;                     // 1
  unsigned int* ticket = (unsigned int*)(loss_acc + 1);  // 1

  // 43008 work-rows (norm-cast B+NNEG, possim B*P), 4 waves/block
  prep_kernel<<<(B + NNEG + B * P) / 4, 256, 0, stream>>>(
      anc, pos, neg, a_bf, n_bf, pos_sim, loss_acc, ticket);

  negsim_mfma_kernel<<<4096, 256, 0, stream>>>(a_bf, n_bf, part_s);

  loss_kernel<<<B / 16, 256, 0, stream>>>(part_s, pos_sim, counts,
                                          loss_acc, ticket, out);
}